// Round 6
// baseline (1628.894 us; speedup 1.0000x reference)
//
#include <hip/hip_runtime.h>
#include <stdint.h>

// Problem constants
#define T_TOKENS 16384
#define H_DIM 1024
#define E_NUM 8
#define DFF_DIM 4096

// GEMM tiling
#define BMT 128
#define BNT 128
#define MT_CAP 264                       // max padded m-tiles: ceil((32768+8*127)/128)
#define PAD_ROWS (MT_CAP * BMT)          // 33792
#define NCHUNK 8
#define MT_PER_CHUNK (MT_CAP / NCHUNK)   // 33
#define CHUNK_ROWS (MT_PER_CHUNK * BMT)  // 4224

// Workspace layout (bytes)
#define WS_COUNTS     0
#define WS_CURSOR     32
#define WS_OFFS       64
#define WS_SLOT_TOK   256
#define WS_EIDX       270592
#define WS_EW         401664
#define WS_TOKSLOT    532736
#define WS_WC1        663808
#define WS_WC2        67772672
#define WS_XB         134881536
#define WS_HDN        168435968          // CHUNK_ROWS x DFF bf16 = 34,603,008
#define WS_Y          203038976          // PAD_ROWS x H bf16 = 69,206,016
#define WS_REQUIRED   272244992UL        // <= 273,162,496 proven available (round 0)
#define WS_SMALL_ZERO 270592

typedef __attribute__((ext_vector_type(8))) short short8;
typedef __attribute__((ext_vector_type(4))) float f32x4;

__device__ __forceinline__ unsigned short f2bf(float f) {
  union { float f; unsigned int u; } v; v.f = f;
  unsigned int r = v.u + 0x7FFFu + ((v.u >> 16) & 1u);  // round-nearest-even
  return (unsigned short)(r >> 16);
}

__device__ __forceinline__ float bf2f(unsigned short b) {
  union { unsigned int u; float f; } v; v.u = ((unsigned int)b) << 16;
  return v.f;
}

__device__ __forceinline__ void load_lds16(const void* g, void* l) {
  __builtin_amdgcn_global_load_lds(
      (const __attribute__((address_space(1))) void*)g,
      (__attribute__((address_space(3))) void*)l, 16, 0, 0);
}

// ---------------------------------------------------------------------------
// Weight fp32 -> bf16 conversion (both fc1_w and fc2_w, same element count)
// ---------------------------------------------------------------------------
__global__ void convert_weights(const float* __restrict__ w1,
                                const float* __restrict__ w2,
                                unsigned short* __restrict__ wc1,
                                unsigned short* __restrict__ wc2) {
  int i = blockIdx.x * blockDim.x + threadIdx.x;  // 0 .. 8388607 (33554432/4)
  const float4* s1 = (const float4*)w1;
  const float4* s2 = (const float4*)w2;
  float4 a = s1[i];
  float4 b = s2[i];
  ushort4 ua, ub;
  ua.x = f2bf(a.x); ua.y = f2bf(a.y); ua.z = f2bf(a.z); ua.w = f2bf(a.w);
  ub.x = f2bf(b.x); ub.y = f2bf(b.y); ub.z = f2bf(b.z); ub.w = f2bf(b.w);
  ((ushort4*)wc1)[i] = ua;
  ((ushort4*)wc2)[i] = ub;
}

// ---------------------------------------------------------------------------
// Router: NO global atomics (round-2 lesson: 32K same-line atomicAdds
// serialize at ~28cy each = 380us). Also emits x as bf16 (xb).
// ---------------------------------------------------------------------------
__global__ __launch_bounds__(256) void router_kernel(
    const float* __restrict__ x, const float* __restrict__ rw,
    const float* __restrict__ rb, unsigned short* __restrict__ xb,
    int* __restrict__ eidx, float* __restrict__ ew) {
  __shared__ float4 rws[E_NUM * 256];  // 8 experts x 1024 floats = 32 KB
  const int tid = threadIdx.x;
#pragma unroll
  for (int k = 0; k < 8; ++k) rws[k * 256 + tid] = ((const float4*)rw)[k * 256 + tid];
  __syncthreads();

  const int wave = tid >> 6;
  const int lane = tid & 63;
#pragma unroll
  for (int i = 0; i < 4; ++i) {
    const int t = blockIdx.x * 16 + wave * 4 + i;
    const float4* xrow = (const float4*)(x + (size_t)t * H_DIM);
    float4 xv[4];
#pragma unroll
    for (int j = 0; j < 4; ++j) xv[j] = xrow[j * 64 + lane];

    ushort4* xbrow = (ushort4*)(xb + (size_t)t * H_DIM);
#pragma unroll
    for (int j = 0; j < 4; ++j) {
      ushort4 o;
      o.x = f2bf(xv[j].x); o.y = f2bf(xv[j].y);
      o.z = f2bf(xv[j].z); o.w = f2bf(xv[j].w);
      xbrow[j * 64 + lane] = o;
    }

    float s[E_NUM];
#pragma unroll
    for (int e = 0; e < E_NUM; ++e) {
      float a = 0.f;
#pragma unroll
      for (int j = 0; j < 4; ++j) {
        float4 wv = rws[e * 256 + j * 64 + lane];
        a += xv[j].x * wv.x + xv[j].y * wv.y + xv[j].z * wv.z + xv[j].w * wv.w;
      }
      s[e] = a;
    }
#pragma unroll
    for (int off = 32; off; off >>= 1) {
#pragma unroll
      for (int e = 0; e < E_NUM; ++e) s[e] += __shfl_xor(s[e], off);
    }
    if (lane == 0) {
      float lg[E_NUM];
#pragma unroll
      for (int e = 0; e < E_NUM; ++e) lg[e] = s[e] + rb[e];
      int i0 = 0; float m0 = lg[0];
#pragma unroll
      for (int e = 1; e < E_NUM; ++e)
        if (lg[e] > m0) { m0 = lg[e]; i0 = e; }
      int i1 = -1; float m1 = -3.4e38f;
#pragma unroll
      for (int e = 0; e < E_NUM; ++e)
        if (e != i0 && lg[e] > m1) { m1 = lg[e]; i1 = e; }
      float e1 = expf(m1 - m0);
      float denom = 1.f + e1;
      ((int2*)eidx)[t] = make_int2(i0, i1);
      ((float2*)ew)[t] = make_float2(1.f / denom, e1 / denom);
    }
  }
}

// ---------------------------------------------------------------------------
// count_kernel: single block, register histogram, LDS atomics only.
// ---------------------------------------------------------------------------
__global__ __launch_bounds__(1024) void count_kernel(const int* __restrict__ eidx,
                                                     int* __restrict__ counts,
                                                     int* __restrict__ offs,
                                                     int* __restrict__ cursor) {
  __shared__ int hist[E_NUM];
  const int tid = threadIdx.x;
  const int lane = tid & 63;
  if (tid < E_NUM) hist[tid] = 0;
  __syncthreads();
  int c[E_NUM];
#pragma unroll
  for (int e = 0; e < E_NUM; ++e) c[e] = 0;
  const int4* p = (const int4*)eidx;  // 32768 ints = 8192 int4
#pragma unroll
  for (int i = 0; i < 8; ++i) {
    int4 v = p[i * 1024 + tid];
#pragma unroll
    for (int e = 0; e < E_NUM; ++e)
      c[e] += (v.x == e) + (v.y == e) + (v.z == e) + (v.w == e);
  }
#pragma unroll
  for (int off = 32; off; off >>= 1) {
#pragma unroll
    for (int e = 0; e < E_NUM; ++e) c[e] += __shfl_xor(c[e], off);
  }
  if (lane == 0) {
#pragma unroll
    for (int e = 0; e < E_NUM; ++e) atomicAdd(&hist[e], c[e]);
  }
  __syncthreads();
  if (tid == 0) {
    int acc = 0;
    offs[0] = 0;
#pragma unroll
    for (int e = 0; e < E_NUM; ++e) {
      counts[e] = hist[e];
      cursor[e] = 0;
      acc += ((hist[e] + BMT - 1) / BMT) * BMT;
      offs[e + 1] = acc;
    }
  }
}

// ---------------------------------------------------------------------------
// Scatter: ballot-rank compaction (128 global atomics total). Also records
// tokslot[t][k] = slot index, enabling the atomic-free gather combine.
// ---------------------------------------------------------------------------
__global__ __launch_bounds__(1024) void scatter_kernel(
    const int* __restrict__ eidx, const int* __restrict__ offs,
    int* __restrict__ cursor, int* __restrict__ slot_token,
    int* __restrict__ tokslot) {
  __shared__ int wcnt[16][E_NUM];
  __shared__ int wpre[16][E_NUM];
  __shared__ int bbase[E_NUM];
  __shared__ int soffs[E_NUM];
  const int tid = threadIdx.x, w = tid >> 6, lane = tid & 63;
  const int t = blockIdx.x * 1024 + tid;
  const int2 epair = ((const int2*)eidx)[t];
  const int e0 = epair.x, e1 = epair.y;
  const unsigned long long lt = (1ULL << lane) - 1ULL;
  if (tid < E_NUM) soffs[tid] = offs[tid];
  int r0 = 0, r1 = 0;
#pragma unroll
  for (int e = 0; e < E_NUM; ++e) {
    unsigned long long m0 = __ballot(e0 == e);
    unsigned long long m1 = __ballot(e1 == e);
    int c0 = __popcll(m0);
    if (e0 == e) r0 = __popcll(m0 & lt);
    if (e1 == e) r1 = c0 + __popcll(m1 & lt);
    if (lane == 0) wcnt[w][e] = c0 + __popcll(m1);
  }
  __syncthreads();
  if (tid < E_NUM) {
    int run = 0;
#pragma unroll
    for (int w2 = 0; w2 < 16; ++w2) {
      wpre[w2][tid] = run;
      run += wcnt[w2][tid];
    }
    bbase[tid] = atomicAdd(&cursor[tid], run);
  }
  __syncthreads();
  const int s0 = soffs[e0] + bbase[e0] + wpre[w][e0] + r0;
  const int s1 = soffs[e1] + bbase[e1] + wpre[w][e1] + r1;
  slot_token[s0] = t;
  slot_token[s1] = t;
  ((int2*)tokslot)[t] = make_int2(s0, s1);
}

// ---------------------------------------------------------------------------
// GEMM core, generalized over BK: C[128x128] = A[128xK] * B[128xK]^T.
// NLD = 128*BK/2048 staging calls per operand per K-step; per-lane source
// pointers allow gathered A rows. 4 waves, each owns a 64x64 C quadrant.
// ---------------------------------------------------------------------------
template <int KTOT, int BK, int NLD>
__device__ __forceinline__ void gemm_core(const unsigned short* const* aptr,
                                          const unsigned short* const* bptr,
                                          unsigned short* lA, unsigned short* lB,
                                          f32x4 acc[4][4]) {
  const int tid = threadIdx.x;
  const int w = tid >> 6, lane = tid & 63;
  const int wm = w >> 1, wn = w & 1;
  const int rrow = lane & 15;
  const int rq = lane >> 4;

  for (int ks = 0; ks < KTOT / BK; ++ks) {
    const int k0 = ks * BK;
#pragma unroll
    for (int i = 0; i < NLD; ++i) {
      load_lds16(aptr[i] + k0, lA + i * 2048 + w * 512);
      load_lds16(bptr[i] + k0, lB + i * 2048 + w * 512);
    }
    __syncthreads();
#pragma unroll
    for (int kk = 0; kk < BK / 32; ++kk) {
      short8 af[4], bfr[4];
#pragma unroll
      for (int mi = 0; mi < 4; ++mi)
        af[mi] = *(const short8*)(lA + (wm * 64 + mi * 16 + rrow) * BK + kk * 32 + rq * 8);
#pragma unroll
      for (int ni = 0; ni < 4; ++ni)
        bfr[ni] = *(const short8*)(lB + (wn * 64 + ni * 16 + rrow) * BK + kk * 32 + rq * 8);
#pragma unroll
      for (int mi = 0; mi < 4; ++mi)
#pragma unroll
        for (int ni = 0; ni < 4; ++ni)
          acc[mi][ni] = __builtin_amdgcn_mfma_f32_16x16x32_bf16(af[mi], bfr[ni], acc[mi][ni], 0, 0, 0);
    }
    __syncthreads();
  }
}

// ---------------------------------------------------------------------------
// fc1: hdn = relu(gather(xb) @ W1^T + b1); BK=64 (m97-ceiling structure).
// ---------------------------------------------------------------------------
__global__ __launch_bounds__(256, 2) void fc1_kernel(
    const unsigned short* __restrict__ xb, const unsigned short* __restrict__ wc1,
    const float* __restrict__ fc1_b, const int* __restrict__ offs,
    const int* __restrict__ counts, const int* __restrict__ slot_token,
    unsigned short* __restrict__ hdn, int chunk) {
  __shared__ unsigned short sA[BMT * 64];
  __shared__ unsigned short sB[BNT * 64];
  const int mt = chunk * MT_PER_CHUNK + blockIdx.y;
  const int row0 = mt * BMT;
  if (row0 >= offs[E_NUM]) return;
  int e = 0;
#pragma unroll
  for (int i = 1; i < E_NUM; ++i) e = (row0 >= offs[i]) ? i : e;
  const int n0 = blockIdx.x * BNT;

  f32x4 acc[4][4];
  f32x4 zf = {0.f, 0.f, 0.f, 0.f};
#pragma unroll
  for (int mi = 0; mi < 4; ++mi)
#pragma unroll
    for (int ni = 0; ni < 4; ++ni) acc[mi][ni] = zf;

  const int tid = threadIdx.x;
  const int srow = tid >> 3;            // BK=64: 8 lanes/row
  const int scol = (tid & 7) * 8;
  const unsigned short* Bm = wc1 + (size_t)e * DFF_DIM * H_DIM + (size_t)n0 * H_DIM;
  const unsigned short* aptr[4];
  const unsigned short* bptr[4];
#pragma unroll
  for (int i = 0; i < 4; ++i) {
    const int r = i * 32 + srow;
    const int tok = slot_token[row0 + r];
    aptr[i] = xb + (size_t)tok * H_DIM + scol;
    bptr[i] = Bm + (size_t)r * H_DIM + scol;
  }
  gemm_core<H_DIM, 64, 4>(aptr, bptr, sA, sB, acc);

  const int w = tid >> 6;
  const int lane = tid & 63;
  const int wm = w >> 1, wn = w & 1;
  const int rrow = lane & 15, rq = lane >> 4;
  const int cnt = counts[e];
  const int lbase = row0 - offs[e];
  const int hrow0 = row0 - chunk * CHUNK_ROWS;
#pragma unroll
  for (int mi = 0; mi < 4; ++mi) {
#pragma unroll
    for (int j = 0; j < 4; ++j) {
      const int rit = wm * 64 + mi * 16 + rq * 4 + j;
      if (lbase + rit >= cnt) continue;
      unsigned short* hrow = hdn + (size_t)(hrow0 + rit) * DFF_DIM;
#pragma unroll
      for (int ni = 0; ni < 4; ++ni) {
        const int n = n0 + wn * 64 + ni * 16 + rrow;
        float v = acc[mi][ni][j] + fc1_b[e * DFF_DIM + n];
        v = v > 0.f ? v : 0.f;
        hrow[n] = f2bf(v);
      }
    }
  }
}

// ---------------------------------------------------------------------------
// fc2: y[slot] = hdn @ W2^T + b2 (bf16 plain stores, full-size y, NO atomics).
// BK=128: halves the per-K-step barrier-drain count (round-5 diagnosis: fc2
// staging at 6.8 TB/s vs fc1 13.5 with identical instrs -> drain-latency
// amortization at low blocks/CU). 64 KB LDS is free (grid-limited occupancy).
// 1-D grid: n = bid&7 (XCD-aligned B-strips), m = bid>>3.
// ---------------------------------------------------------------------------
__global__ __launch_bounds__(256, 2) void fc2_kernel(
    const unsigned short* __restrict__ hdn, const unsigned short* __restrict__ wc2,
    const float* __restrict__ fc2_b, const int* __restrict__ offs,
    const int* __restrict__ counts, unsigned short* __restrict__ y, int chunk) {
  __shared__ unsigned short sA[BMT * 128];
  __shared__ unsigned short sB[BNT * 128];
  const int mt_local = blockIdx.x >> 3;
  const int mt = chunk * MT_PER_CHUNK + mt_local;
  const int row0 = mt * BMT;
  if (row0 >= offs[E_NUM]) return;
  int e = 0;
#pragma unroll
  for (int i = 1; i < E_NUM; ++i) e = (row0 >= offs[i]) ? i : e;
  const int n0 = (blockIdx.x & 7) * BNT;

  f32x4 acc[4][4];
  f32x4 zf = {0.f, 0.f, 0.f, 0.f};
#pragma unroll
  for (int mi = 0; mi < 4; ++mi)
#pragma unroll
    for (int ni = 0; ni < 4; ++ni) acc[mi][ni] = zf;

  const int tid = threadIdx.x;
  const int srow = tid >> 4;            // BK=128: 16 lanes/row
  const int scol = (tid & 15) * 8;
  const unsigned short* A = hdn + (size_t)(mt_local * BMT) * DFF_DIM;
  const unsigned short* Bm = wc2 + (size_t)e * H_DIM * DFF_DIM + (size_t)n0 * DFF_DIM;
  const unsigned short* aptr[8];
  const unsigned short* bptr[8];
#pragma unroll
  for (int i = 0; i < 8; ++i) {
    const int r = i * 16 + srow;
    aptr[i] = A + (size_t)r * DFF_DIM + scol;
    bptr[i] = Bm + (size_t)r * DFF_DIM + scol;
  }
  gemm_core<DFF_DIM, 128, 8>(aptr, bptr, sA, sB, acc);

  const int w = tid >> 6;
  const int lane = tid & 63;
  const int wm = w >> 1, wn = w & 1;
  const int rrow = lane & 15, rq = lane >> 4;
  const int cnt = counts[e];
  const int lbase = row0 - offs[e];
#pragma unroll
  for (int mi = 0; mi < 4; ++mi) {
#pragma unroll
    for (int j = 0; j < 4; ++j) {
      const int rit = wm * 64 + mi * 16 + rq * 4 + j;
      if (lbase + rit >= cnt) continue;
      unsigned short* yrow = y + (size_t)(row0 + rit) * H_DIM;
#pragma unroll
      for (int ni = 0; ni < 4; ++ni) {
        const int h = n0 + wn * 64 + ni * 16 + rrow;
        yrow[h] = f2bf(acc[mi][ni][j] + fc2_b[e * H_DIM + h]);
      }
    }
  }
}

// ---------------------------------------------------------------------------
// combine (gather, atomic-free, deterministic): out[t] = w0*y[s0] + w1*y[s1].
// One wave per token; fully overwrites out (no memset needed).
// ---------------------------------------------------------------------------
__global__ __launch_bounds__(256) void combine_kernel(
    const unsigned short* __restrict__ y, const int* __restrict__ tokslot,
    const float* __restrict__ ew, float* __restrict__ out) {
  const int wave = threadIdx.x >> 6;
  const int lane = threadIdx.x & 63;
  const int t = blockIdx.x * 4 + wave;
  const int2 sl = ((const int2*)tokslot)[t];
  const float2 wp = ((const float2*)ew)[t];
  const ushort4* y0 = (const ushort4*)(y + (size_t)sl.x * H_DIM);
  const ushort4* y1 = (const ushort4*)(y + (size_t)sl.y * H_DIM);
  float4* orow = (float4*)(out + (size_t)t * H_DIM);
#pragma unroll
  for (int j = 0; j < 4; ++j) {
    const int idx = j * 64 + lane;
    ushort4 a = y0[idx];
    ushort4 b = y1[idx];
    float4 r;
    r.x = wp.x * bf2f(a.x) + wp.y * bf2f(b.x);
    r.y = wp.x * bf2f(a.y) + wp.y * bf2f(b.y);
    r.z = wp.x * bf2f(a.z) + wp.y * bf2f(b.z);
    r.w = wp.x * bf2f(a.w) + wp.y * bf2f(b.w);
    orow[idx] = r;
  }
}

// ---------------------------------------------------------------------------
extern "C" void kernel_launch(void* const* d_in, const int* in_sizes, int n_in,
                              void* d_out, int out_size, void* d_ws, size_t ws_size,
                              hipStream_t stream) {
  const float* x        = (const float*)d_in[0];
  const float* router_w = (const float*)d_in[1];
  const float* router_b = (const float*)d_in[2];
  const float* fc1_w    = (const float*)d_in[3];
  const float* fc1_b    = (const float*)d_in[4];
  const float* fc2_w    = (const float*)d_in[5];
  const float* fc2_b    = (const float*)d_in[6];
  float* out = (float*)d_out;

  char* ws = (char*)d_ws;
  int* counts            = (int*)(ws + WS_COUNTS);
  int* cursor            = (int*)(ws + WS_CURSOR);
  int* offs              = (int*)(ws + WS_OFFS);
  int* slot_token        = (int*)(ws + WS_SLOT_TOK);
  int* eidx              = (int*)(ws + WS_EIDX);
  float* ew              = (float*)(ws + WS_EW);
  int* tokslot           = (int*)(ws + WS_TOKSLOT);
  unsigned short* wc1    = (unsigned short*)(ws + WS_WC1);
  unsigned short* wc2    = (unsigned short*)(ws + WS_WC2);
  unsigned short* xb     = (unsigned short*)(ws + WS_XB);
  unsigned short* hdn    = (unsigned short*)(ws + WS_HDN);
  unsigned short* y      = (unsigned short*)(ws + WS_Y);

  if (ws_size < WS_REQUIRED) {
    hipMemsetAsync(d_out, 0, (size_t)T_TOKENS * H_DIM * sizeof(float), stream);
    return;  // output stays zero -> diagnosable failure
  }
  hipMemsetAsync(ws, 0, WS_SMALL_ZERO, stream);  // zero counts/cursor/offs/slot_token

  convert_weights<<<32768, 256, 0, stream>>>(fc1_w, fc2_w, wc1, wc2);
  router_kernel<<<T_TOKENS / 16, 256, 0, stream>>>(x, router_w, router_b, xb, eidx, ew);
  count_kernel<<<1, 1024, 0, stream>>>(eidx, counts, offs, cursor);
  scatter_kernel<<<T_TOKENS / 1024, 1024, 0, stream>>>(eidx, offs, cursor, slot_token, tokslot);

  for (int c = 0; c < NCHUNK; ++c) {
    fc1_kernel<<<dim3(DFF_DIM / BNT, MT_PER_CHUNK), 256, 0, stream>>>(
        xb, wc1, fc1_b, offs, counts, slot_token, hdn, c);
    fc2_kernel<<<E_NUM * MT_PER_CHUNK, 256, 0, stream>>>(
        hdn, wc2, fc2_b, offs, counts, y, c);
  }
  combine_kernel<<<T_TOKENS / 4, 256, 0, stream>>>(y, tokslot, ew, out);
}

// Round 7
// 1043.503 us; speedup vs baseline: 1.5610x; 1.5610x over previous
//
#include <hip/hip_runtime.h>
#include <stdint.h>

// Problem constants
#define T_TOKENS 16384
#define H_DIM 1024
#define E_NUM 8
#define DFF_DIM 4096

// GEMM tiling
#define BMT 128
#define BNT 128
#define BKT 64
#define MT_CAP 264                       // max padded m-tiles: ceil((32768+8*127)/128)
#define PAD_ROWS (MT_CAP * BMT)          // 33792
#define NCHUNK 4
#define MT_PER_CHUNK (MT_CAP / NCHUNK)   // 66
#define CHUNK_ROWS (MT_PER_CHUNK * BMT)  // 8448

// Workspace layout (bytes)
#define WS_COUNTS     0
#define WS_CURSOR     32
#define WS_OFFS       64
#define WS_SLOT_TOK   256
#define WS_SLOT_W     135424
#define WS_EIDX       270592
#define WS_EW         401664
#define WS_WC1        532736
#define WS_WC2        67641600
#define WS_XB         134750464
#define WS_HDN        168304896          // CHUNK_ROWS x DFF bf16 = 69,206,016
#define WS_OUTK1      237510912          // T x H bf16 = 33,554,432
#define WS_REQUIRED   271065344UL        // <= 273,162,496 proven available (round 0)
#define WS_SMALL_ZERO 270592

typedef __attribute__((ext_vector_type(8))) short short8;
typedef __attribute__((ext_vector_type(4))) float f32x4;

__device__ __forceinline__ unsigned short f2bf(float f) {
  union { float f; unsigned int u; } v; v.f = f;
  unsigned int r = v.u + 0x7FFFu + ((v.u >> 16) & 1u);  // round-nearest-even
  return (unsigned short)(r >> 16);
}

__device__ __forceinline__ float bf2f(unsigned short b) {
  union { unsigned int u; float f; } v; v.u = ((unsigned int)b) << 16;
  return v.f;
}

__device__ __forceinline__ void load_lds16(const void* g, void* l) {
  __builtin_amdgcn_global_load_lds(
      (const __attribute__((address_space(1))) void*)g,
      (__attribute__((address_space(3))) void*)l, 16, 0, 0);
}

// ---------------------------------------------------------------------------
// Weight fp32 -> bf16 conversion (both fc1_w and fc2_w, same element count)
// ---------------------------------------------------------------------------
__global__ void convert_weights(const float* __restrict__ w1,
                                const float* __restrict__ w2,
                                unsigned short* __restrict__ wc1,
                                unsigned short* __restrict__ wc2) {
  int i = blockIdx.x * blockDim.x + threadIdx.x;  // 0 .. 8388607 (33554432/4)
  const float4* s1 = (const float4*)w1;
  const float4* s2 = (const float4*)w2;
  float4 a = s1[i];
  float4 b = s2[i];
  ushort4 ua, ub;
  ua.x = f2bf(a.x); ua.y = f2bf(a.y); ua.z = f2bf(a.z); ua.w = f2bf(a.w);
  ub.x = f2bf(b.x); ub.y = f2bf(b.y); ub.z = f2bf(b.z); ub.w = f2bf(b.w);
  ((ushort4*)wc1)[i] = ua;
  ((ushort4*)wc2)[i] = ub;
}

// ---------------------------------------------------------------------------
// Router: NO global atomics (round-2 lesson: 32K same-line atomicAdds
// serialize at ~28cy each = 380us). Also emits x as bf16 (xb).
// ---------------------------------------------------------------------------
__global__ __launch_bounds__(256) void router_kernel(
    const float* __restrict__ x, const float* __restrict__ rw,
    const float* __restrict__ rb, unsigned short* __restrict__ xb,
    int* __restrict__ eidx, float* __restrict__ ew) {
  __shared__ float4 rws[E_NUM * 256];  // 8 experts x 1024 floats = 32 KB
  const int tid = threadIdx.x;
#pragma unroll
  for (int k = 0; k < 8; ++k) rws[k * 256 + tid] = ((const float4*)rw)[k * 256 + tid];
  __syncthreads();

  const int wave = tid >> 6;
  const int lane = tid & 63;
#pragma unroll
  for (int i = 0; i < 4; ++i) {
    const int t = blockIdx.x * 16 + wave * 4 + i;
    const float4* xrow = (const float4*)(x + (size_t)t * H_DIM);
    float4 xv[4];
#pragma unroll
    for (int j = 0; j < 4; ++j) xv[j] = xrow[j * 64 + lane];

    ushort4* xbrow = (ushort4*)(xb + (size_t)t * H_DIM);
#pragma unroll
    for (int j = 0; j < 4; ++j) {
      ushort4 o;
      o.x = f2bf(xv[j].x); o.y = f2bf(xv[j].y);
      o.z = f2bf(xv[j].z); o.w = f2bf(xv[j].w);
      xbrow[j * 64 + lane] = o;
    }

    float s[E_NUM];
#pragma unroll
    for (int e = 0; e < E_NUM; ++e) {
      float a = 0.f;
#pragma unroll
      for (int j = 0; j < 4; ++j) {
        float4 wv = rws[e * 256 + j * 64 + lane];
        a += xv[j].x * wv.x + xv[j].y * wv.y + xv[j].z * wv.z + xv[j].w * wv.w;
      }
      s[e] = a;
    }
#pragma unroll
    for (int off = 32; off; off >>= 1) {
#pragma unroll
      for (int e = 0; e < E_NUM; ++e) s[e] += __shfl_xor(s[e], off);
    }
    if (lane == 0) {
      float lg[E_NUM];
#pragma unroll
      for (int e = 0; e < E_NUM; ++e) lg[e] = s[e] + rb[e];
      int i0 = 0; float m0 = lg[0];
#pragma unroll
      for (int e = 1; e < E_NUM; ++e)
        if (lg[e] > m0) { m0 = lg[e]; i0 = e; }
      int i1 = -1; float m1 = -3.4e38f;
#pragma unroll
      for (int e = 0; e < E_NUM; ++e)
        if (e != i0 && lg[e] > m1) { m1 = lg[e]; i1 = e; }
      float e1 = expf(m1 - m0);
      float denom = 1.f + e1;
      ((int2*)eidx)[t] = make_int2(i0, i1);
      ((float2*)ew)[t] = make_float2(1.f / denom, e1 / denom);
    }
  }
}

// ---------------------------------------------------------------------------
// count_kernel: single block, register histogram, LDS atomics only.
// ---------------------------------------------------------------------------
__global__ __launch_bounds__(1024) void count_kernel(const int* __restrict__ eidx,
                                                     int* __restrict__ counts,
                                                     int* __restrict__ offs,
                                                     int* __restrict__ cursor) {
  __shared__ int hist[E_NUM];
  const int tid = threadIdx.x;
  const int lane = tid & 63;
  if (tid < E_NUM) hist[tid] = 0;
  __syncthreads();
  int c[E_NUM];
#pragma unroll
  for (int e = 0; e < E_NUM; ++e) c[e] = 0;
  const int4* p = (const int4*)eidx;  // 32768 ints = 8192 int4
#pragma unroll
  for (int i = 0; i < 8; ++i) {
    int4 v = p[i * 1024 + tid];
#pragma unroll
    for (int e = 0; e < E_NUM; ++e)
      c[e] += (v.x == e) + (v.y == e) + (v.z == e) + (v.w == e);
  }
#pragma unroll
  for (int off = 32; off; off >>= 1) {
#pragma unroll
    for (int e = 0; e < E_NUM; ++e) c[e] += __shfl_xor(c[e], off);
  }
  if (lane == 0) {
#pragma unroll
    for (int e = 0; e < E_NUM; ++e) atomicAdd(&hist[e], c[e]);
  }
  __syncthreads();
  if (tid == 0) {
    int acc = 0;
    offs[0] = 0;
#pragma unroll
    for (int e = 0; e < E_NUM; ++e) {
      counts[e] = hist[e];
      cursor[e] = 0;
      acc += ((hist[e] + BMT - 1) / BMT) * BMT;
      offs[e + 1] = acc;
    }
  }
}

// ---------------------------------------------------------------------------
// Scatter: ballot-rank compaction (128 global atomics total). slot_token
// carries the k-flag in bit 31 (k=0 -> fp32 direct-out path, k=1 -> outk1).
// ---------------------------------------------------------------------------
__global__ __launch_bounds__(1024) void scatter_kernel(
    const int* __restrict__ eidx, const float* __restrict__ ew,
    const int* __restrict__ offs, int* __restrict__ cursor,
    int* __restrict__ slot_token, float* __restrict__ slot_w) {
  __shared__ int wcnt[16][E_NUM];
  __shared__ int wpre[16][E_NUM];
  __shared__ int bbase[E_NUM];
  __shared__ int soffs[E_NUM];
  const int tid = threadIdx.x, w = tid >> 6, lane = tid & 63;
  const int t = blockIdx.x * 1024 + tid;
  const int2 epair = ((const int2*)eidx)[t];
  const float2 wpair = ((const float2*)ew)[t];
  const int e0 = epair.x, e1 = epair.y;
  const unsigned long long lt = (1ULL << lane) - 1ULL;
  if (tid < E_NUM) soffs[tid] = offs[tid];
  int r0 = 0, r1 = 0;
#pragma unroll
  for (int e = 0; e < E_NUM; ++e) {
    unsigned long long m0 = __ballot(e0 == e);
    unsigned long long m1 = __ballot(e1 == e);
    int c0 = __popcll(m0);
    if (e0 == e) r0 = __popcll(m0 & lt);
    if (e1 == e) r1 = c0 + __popcll(m1 & lt);
    if (lane == 0) wcnt[w][e] = c0 + __popcll(m1);
  }
  __syncthreads();
  if (tid < E_NUM) {
    int run = 0;
#pragma unroll
    for (int w2 = 0; w2 < 16; ++w2) {
      wpre[w2][tid] = run;
      run += wcnt[w2][tid];
    }
    bbase[tid] = atomicAdd(&cursor[tid], run);
  }
  __syncthreads();
  const int s0 = soffs[e0] + bbase[e0] + wpre[w][e0] + r0;
  const int s1 = soffs[e1] + bbase[e1] + wpre[w][e1] + r1;
  slot_token[s0] = t;                       // k=0
  slot_w[s0] = wpair.x;
  slot_token[s1] = t | (int)0x80000000;     // k=1
  slot_w[s1] = wpair.y;
}

// ---------------------------------------------------------------------------
// GEMM core (BK=64, round-5 proven): C[128x128] = A[128xK] * B[128xK]^T.
// Per-lane staging source pointers allow gathered A rows. 4 waves, each owns
// a 64x64 C quadrant.
// ---------------------------------------------------------------------------
template <int KTOT>
__device__ __forceinline__ void gemm_core(const unsigned short* const* aptr,
                                          const unsigned short* const* bptr,
                                          unsigned short* lA, unsigned short* lB,
                                          f32x4 acc[4][4]) {
  const int tid = threadIdx.x;
  const int w = tid >> 6, lane = tid & 63;
  const int wm = w >> 1, wn = w & 1;
  const int rrow = lane & 15;
  const int rq = lane >> 4;

  for (int ks = 0; ks < KTOT / BKT; ++ks) {
    const int k0 = ks * BKT;
#pragma unroll
    for (int i = 0; i < 4; ++i) {
      load_lds16(aptr[i] + k0, lA + i * 2048 + w * 512);
      load_lds16(bptr[i] + k0, lB + i * 2048 + w * 512);
    }
    __syncthreads();
#pragma unroll
    for (int kk = 0; kk < 2; ++kk) {
      short8 af[4], bfr[4];
#pragma unroll
      for (int mi = 0; mi < 4; ++mi)
        af[mi] = *(const short8*)(lA + (wm * 64 + mi * 16 + rrow) * BKT + kk * 32 + rq * 8);
#pragma unroll
      for (int ni = 0; ni < 4; ++ni)
        bfr[ni] = *(const short8*)(lB + (wn * 64 + ni * 16 + rrow) * BKT + kk * 32 + rq * 8);
#pragma unroll
      for (int mi = 0; mi < 4; ++mi)
#pragma unroll
        for (int ni = 0; ni < 4; ++ni)
          acc[mi][ni] = __builtin_amdgcn_mfma_f32_16x16x32_bf16(af[mi], bfr[ni], acc[mi][ni], 0, 0, 0);
    }
    __syncthreads();
  }
}

// ---------------------------------------------------------------------------
// fc1: hdn = relu(gather(xb) @ W1^T + b1); BK=64 (m97-ceiling structure,
// measured 886 TF). A gathered via slot_token in the gload_lds source addrs.
// ---------------------------------------------------------------------------
__global__ __launch_bounds__(256, 2) void fc1_kernel(
    const unsigned short* __restrict__ xb, const unsigned short* __restrict__ wc1,
    const float* __restrict__ fc1_b, const int* __restrict__ offs,
    const int* __restrict__ counts, const int* __restrict__ slot_token,
    unsigned short* __restrict__ hdn, int chunk) {
  __shared__ unsigned short sA[BMT * BKT];
  __shared__ unsigned short sB[BNT * BKT];
  const int mt = chunk * MT_PER_CHUNK + blockIdx.y;
  const int row0 = mt * BMT;
  if (row0 >= offs[E_NUM]) return;
  int e = 0;
#pragma unroll
  for (int i = 1; i < E_NUM; ++i) e = (row0 >= offs[i]) ? i : e;
  const int n0 = blockIdx.x * BNT;

  f32x4 acc[4][4];
  f32x4 zf = {0.f, 0.f, 0.f, 0.f};
#pragma unroll
  for (int mi = 0; mi < 4; ++mi)
#pragma unroll
    for (int ni = 0; ni < 4; ++ni) acc[mi][ni] = zf;

  const int tid = threadIdx.x;
  const int srow = tid >> 3;            // 8 lanes/row (16B each over BK=64)
  const int scol = (tid & 7) * 8;
  const unsigned short* Bm = wc1 + (size_t)e * DFF_DIM * H_DIM + (size_t)n0 * H_DIM;
  const unsigned short* aptr[4];
  const unsigned short* bptr[4];
#pragma unroll
  for (int i = 0; i < 4; ++i) {
    const int r = i * 32 + srow;
    const int tok = slot_token[row0 + r] & 0x7FFFFFFF;
    aptr[i] = xb + (size_t)tok * H_DIM + scol;
    bptr[i] = Bm + (size_t)r * H_DIM + scol;
  }
  gemm_core<H_DIM>(aptr, bptr, sA, sB, acc);

  const int w = tid >> 6;
  const int lane = tid & 63;
  const int wm = w >> 1, wn = w & 1;
  const int rrow = lane & 15, rq = lane >> 4;
  const int cnt = counts[e];
  const int lbase = row0 - offs[e];
  const int hrow0 = row0 - chunk * CHUNK_ROWS;
#pragma unroll
  for (int mi = 0; mi < 4; ++mi) {
#pragma unroll
    for (int j = 0; j < 4; ++j) {
      const int rit = wm * 64 + mi * 16 + rq * 4 + j;
      if (lbase + rit >= cnt) continue;
      unsigned short* hrow = hdn + (size_t)(hrow0 + rit) * DFF_DIM;
#pragma unroll
      for (int ni = 0; ni < 4; ++ni) {
        const int n = n0 + wn * 64 + ni * 16 + rrow;
        float v = acc[mi][ni][j] + fc1_b[e * DFF_DIM + n];
        v = v > 0.f ? v : 0.f;
        hrow[n] = f2bf(v);
      }
    }
  }
}

// ---------------------------------------------------------------------------
// fc2: BK=64 (round-6 lesson: BK=128 regresses, per guide m132). 2D-chunked
// XCD swizzle (T1): xcd = id&7 gets an 8m x 8n patch so co-resident blocks
// on one XCD share A-tiles AND B-strips in L2 (round-7 diagnosis: n-pinned
// layout read each A-tile once per XCD -> 553MB L3/HBM A-traffic).
// Epilogue: k=0 rows -> w*(acc+b) fp32 direct to out (each token exactly
// once, race-free); k=1 rows -> bf16 to outk1. No atomics anywhere.
// ---------------------------------------------------------------------------
__global__ __launch_bounds__(256, 2) void fc2_kernel(
    const unsigned short* __restrict__ hdn, const unsigned short* __restrict__ wc2,
    const float* __restrict__ fc2_b, const int* __restrict__ offs,
    const int* __restrict__ counts, const int* __restrict__ slot_token,
    const float* __restrict__ slot_w, float* __restrict__ out,
    unsigned short* __restrict__ outk1, int chunk) {
  __shared__ unsigned short sA[BMT * BKT];
  __shared__ unsigned short sB[BNT * BKT];
  // Bijective 2D-chunked XCD swizzle over (66 m) x (8 n) = 528 blocks.
  const int id = blockIdx.x;
  const int xcd = id & 7, j = id >> 3;
  int ml, nt;
  if (j < 64) { ml = xcd * 8 + (j & 7); nt = j >> 3; }
  else        { ml = 64 + (j & 1);      nt = xcd;    }
  const int mt = chunk * MT_PER_CHUNK + ml;
  const int row0 = mt * BMT;
  if (row0 >= offs[E_NUM]) return;
  int e = 0;
#pragma unroll
  for (int i = 1; i < E_NUM; ++i) e = (row0 >= offs[i]) ? i : e;
  const int n0 = nt * BNT;

  f32x4 acc[4][4];
  f32x4 zf = {0.f, 0.f, 0.f, 0.f};
#pragma unroll
  for (int mi = 0; mi < 4; ++mi)
#pragma unroll
    for (int ni = 0; ni < 4; ++ni) acc[mi][ni] = zf;

  const int tid = threadIdx.x;
  const int srow = tid >> 3;
  const int scol = (tid & 7) * 8;
  const unsigned short* A = hdn + (size_t)(ml * BMT) * DFF_DIM;
  const unsigned short* Bm = wc2 + (size_t)e * H_DIM * DFF_DIM + (size_t)n0 * DFF_DIM;
  const unsigned short* aptr[4];
  const unsigned short* bptr[4];
#pragma unroll
  for (int i = 0; i < 4; ++i) {
    const int r = i * 32 + srow;
    aptr[i] = A + (size_t)r * DFF_DIM + scol;
    bptr[i] = Bm + (size_t)r * DFF_DIM + scol;
  }
  gemm_core<DFF_DIM>(aptr, bptr, sA, sB, acc);

  const int w = tid >> 6;
  const int lane = tid & 63;
  const int wm = w >> 1, wn = w & 1;
  const int rrow = lane & 15, rq = lane >> 4;
  const int cnt = counts[e];
  const int lbase = row0 - offs[e];
#pragma unroll
  for (int mi = 0; mi < 4; ++mi) {
#pragma unroll
    for (int j2 = 0; j2 < 4; ++j2) {
      const int rit = wm * 64 + mi * 16 + rq * 4 + j2;
      if (lbase + rit >= cnt) continue;
      const int gr = row0 + rit;
      const int st = slot_token[gr];
      const int tok = st & 0x7FFFFFFF;
      const float wgt = slot_w[gr];
#pragma unroll
      for (int ni = 0; ni < 4; ++ni) {
        const int h = n0 + wn * 64 + ni * 16 + rrow;
        const float v = (acc[mi][ni][j2] + fc2_b[e * H_DIM + h]) * wgt;
        if (st >= 0) out[(size_t)tok * H_DIM + h] = v;            // k=0, fp32
        else         outk1[(size_t)tok * H_DIM + h] = f2bf(v);    // k=1, bf16
      }
    }
  }
}

// ---------------------------------------------------------------------------
// Final add (atomic-free, deterministic): out[t] += bf2f(outk1[t]).
// Per-token unique read-modify-write; out was fully written by k=0 stores.
// ---------------------------------------------------------------------------
__global__ __launch_bounds__(256) void add_kernel(
    float* __restrict__ out, const unsigned short* __restrict__ outk1) {
  const int wave = threadIdx.x >> 6;
  const int lane = threadIdx.x & 63;
  const int t = blockIdx.x * 4 + wave;
  float4* orow = (float4*)(out + (size_t)t * H_DIM);
  const ushort4* krow = (const ushort4*)(outk1 + (size_t)t * H_DIM);
#pragma unroll
  for (int j = 0; j < 4; ++j) {
    const int idx = j * 64 + lane;
    float4 a = orow[idx];
    ushort4 b = krow[idx];
    a.x += bf2f(b.x); a.y += bf2f(b.y); a.z += bf2f(b.z); a.w += bf2f(b.w);
    orow[idx] = a;
  }
}

// ---------------------------------------------------------------------------
extern "C" void kernel_launch(void* const* d_in, const int* in_sizes, int n_in,
                              void* d_out, int out_size, void* d_ws, size_t ws_size,
                              hipStream_t stream) {
  const float* x        = (const float*)d_in[0];
  const float* router_w = (const float*)d_in[1];
  const float* router_b = (const float*)d_in[2];
  const float* fc1_w    = (const float*)d_in[3];
  const float* fc1_b    = (const float*)d_in[4];
  const float* fc2_w    = (const float*)d_in[5];
  const float* fc2_b    = (const float*)d_in[6];
  float* out = (float*)d_out;

  char* ws = (char*)d_ws;
  int* counts            = (int*)(ws + WS_COUNTS);
  int* cursor            = (int*)(ws + WS_CURSOR);
  int* offs              = (int*)(ws + WS_OFFS);
  int* slot_token        = (int*)(ws + WS_SLOT_TOK);
  float* slot_w          = (float*)(ws + WS_SLOT_W);
  int* eidx              = (int*)(ws + WS_EIDX);
  float* ew              = (float*)(ws + WS_EW);
  unsigned short* wc1    = (unsigned short*)(ws + WS_WC1);
  unsigned short* wc2    = (unsigned short*)(ws + WS_WC2);
  unsigned short* xb     = (unsigned short*)(ws + WS_XB);
  unsigned short* hdn    = (unsigned short*)(ws + WS_HDN);
  unsigned short* outk1  = (unsigned short*)(ws + WS_OUTK1);

  if (ws_size < WS_REQUIRED) {
    hipMemsetAsync(d_out, 0, (size_t)T_TOKENS * H_DIM * sizeof(float), stream);
    return;  // output stays zero -> diagnosable failure
  }
  hipMemsetAsync(ws, 0, WS_SMALL_ZERO, stream);  // zero counts/cursor/offs/slot_token/slot_w

  convert_weights<<<32768, 256, 0, stream>>>(fc1_w, fc2_w, wc1, wc2);
  router_kernel<<<T_TOKENS / 16, 256, 0, stream>>>(x, router_w, router_b, xb, eidx, ew);
  count_kernel<<<1, 1024, 0, stream>>>(eidx, counts, offs, cursor);
  scatter_kernel<<<T_TOKENS / 1024, 1024, 0, stream>>>(eidx, ew, offs, cursor, slot_token, slot_w);

  for (int c = 0; c < NCHUNK; ++c) {
    fc1_kernel<<<dim3(DFF_DIM / BNT, MT_PER_CHUNK), 256, 0, stream>>>(
        xb, wc1, fc1_b, offs, counts, slot_token, hdn, c);
    fc2_kernel<<<E_NUM * MT_PER_CHUNK, 256, 0, stream>>>(
        hdn, wc2, fc2_b, offs, counts, slot_token, slot_w, out, outk1, c);
  }
  add_kernel<<<T_TOKENS / 4, 256, 0, stream>>>(out, outk1);
}